// Round 1
// baseline (256.048 us; speedup 1.0000x reference)
//
#include <hip/hip_runtime.h>
#include <cstdint>

#define AS1C(p) ((const __attribute__((address_space(1))) void*)(p))
#define AS3(p)  ((__attribute__((address_space(3))) void*)(p))

typedef __bf16 bf16x8 __attribute__((ext_vector_type(8)));
typedef __bf16 bf16x4 __attribute__((ext_vector_type(4)));
typedef float  f32x4  __attribute__((ext_vector_type(4)));

constexpr int B_ = 32, T_ = 512, D_ = 512, E_ = 8, H_ = 2048;
constexpr int S_ = 16;   // pool blocks per utterance
constexpr int P_ = 32;   // partial slots per utterance (2 per pool block)

// ---------------- fused prep: x->bf16 + partial mean-pool, and W1/W2 transpose+cvt ----------------
__global__ __launch_bounds__(256)
void prep_kernel(const float* __restrict__ x, __bf16* __restrict__ xbf,
                 float* __restrict__ partial /*[B][P_][D]*/,
                 const float* __restrict__ W1, const float* __restrict__ W2,
                 __bf16* __restrict__ w1t, __bf16* __restrict__ w2t) {
  __shared__ float t[64][65];
  const int blk = blockIdx.x;
  const int tid = threadIdx.x;
  if (blk < B_ * S_) {
    const int b = blk >> 4, s = blk & 15;
    const int c = (tid & 127) * 4;
    const int half = tid >> 7;
    const size_t base = (size_t)b * T_ * D_ + (size_t)(s * 32) * D_;
    const float* xb = x + base;
    __bf16* ob = xbf + base;
    f32x4 acc = {0.f, 0.f, 0.f, 0.f};
#pragma unroll
    for (int i = 0; i < 16; ++i) {
      const int tr = half + 2 * i;
      f32x4 v = *reinterpret_cast<const f32x4*>(&xb[(size_t)tr * D_ + c]);
      acc += v;
      bf16x4 h; h[0] = (__bf16)v[0]; h[1] = (__bf16)v[1]; h[2] = (__bf16)v[2]; h[3] = (__bf16)v[3];
      *reinterpret_cast<bf16x4*>(&ob[(size_t)tr * D_ + c]) = h;
    }
    float* p = partial + ((size_t)b * P_ + (s * 2 + half)) * D_ + c;
    *reinterpret_cast<f32x4*>(p) = acc;
  } else {
    const int idx = blk - B_ * S_;
    const int z = idx >> 8;
    const int tt = idx & 255;
    const float* src; __bf16* dst; int R, C;
    if (z < E_) { src = W1 + (size_t)z * D_ * H_; dst = w1t + (size_t)z * D_ * H_; R = D_; C = H_; }
    else        { src = W2 + (size_t)(z - E_) * H_ * D_; dst = w2t + (size_t)(z - E_) * H_ * D_; R = H_; C = D_; }
    const int nTc = C >> 6;
    const int c0 = (tt % nTc) * 64;
    const int r0 = (tt / nTc) * 64;
    const int lx = tid & 15, ly = tid >> 4;
#pragma unroll
    for (int i = 0; i < 4; ++i) {
      const int r = ly + i * 16;
      float4 v = *reinterpret_cast<const float4*>(&src[(size_t)(r0 + r) * C + c0 + lx * 4]);
      t[r][lx * 4 + 0] = v.x; t[r][lx * 4 + 1] = v.y;
      t[r][lx * 4 + 2] = v.z; t[r][lx * 4 + 3] = v.w;
    }
    __syncthreads();
#pragma unroll
    for (int h = 0; h < 2; ++h) {
      const int chunk = tid + h * 256;
      const int cc = chunk >> 3;
      const int rr = (chunk & 7) * 8;
      bf16x8 o;
#pragma unroll
      for (int j = 0; j < 8; ++j) o[j] = (__bf16)t[rr + j][cc];
      *reinterpret_cast<bf16x8*>(&dst[(size_t)(c0 + cc) * R + r0 + rr]) = o;
    }
  }
}

// ---------------- router finisher ----------------
__global__ void router2_kernel(const float* __restrict__ partial, const float* __restrict__ Wp,
                               const float* __restrict__ bp, float* __restrict__ probs_out,
                               float* __restrict__ chosen_out_f, int* __restrict__ chosen_ws) {
  const int b = blockIdx.x;
  const int tid = threadIdx.x;  // 512 threads, one per d
  __shared__ float pooled[D_];
  __shared__ float part[E_][64];
  __shared__ float logits[E_];
  const float* p = partial + (size_t)b * P_ * D_;
  float s = 0.f;
#pragma unroll
  for (int i = 0; i < P_; ++i) s += p[i * D_ + tid];
  pooled[tid] = s * (1.0f / (float)T_);
  __syncthreads();
  const int e = tid >> 6, dl = tid & 63;
  float acc = 0.f;
  for (int d = dl; d < D_; d += 64) acc += pooled[d] * Wp[d * E_ + e];
  part[e][dl] = acc;
  __syncthreads();
  if (tid < E_) {
    float sum = bp[tid];
#pragma unroll
    for (int i = 0; i < 64; ++i) sum += part[tid][i];
    logits[tid] = sum;
  }
  __syncthreads();
  if (tid == 0) {
    float mx = logits[0]; int arg = 0;
    for (int i = 1; i < E_; ++i) if (logits[i] > mx) { mx = logits[i]; arg = i; }
    float ex[E_], se = 0.f;
    for (int i = 0; i < E_; ++i) { ex[i] = expf(logits[i] - mx); se += ex[i]; }
    const float inv = 1.0f / se;
    for (int i = 0; i < E_; ++i) probs_out[b * E_ + i] = ex[i] * inv;
    chosen_out_f[b] = (float)arg;
    chosen_ws[b] = arg;
  }
}

// ---------------- batched GEMM, B^T input, double-buffered 2-phase (T3 minimum recipe) ----------
// C[b] = epilogue(A[b] @ BT[e]^T + bias[e]); A:[512,K] k-contig, BT:[N,K] k-contig.
// Per K-tile: issue 8 global_load_lds for tile t+1 into slot s^1, ds_read+MFMA tile t from
// slot s, then ONE __syncthreads (its vmcnt(0) lands AFTER the MFMA cluster -> load latency
// hidden under compute; one barrier per K-tile instead of two).
// LDS row = 64 bf16 = 8 slots of 16B; slot p of row r holds logical k-slot p^(r&7):
// staging src-k is a pure lane function, fragment reads land 2 lanes/bank (free, m136);
// verified 0 conflicts in the previous rounds.
// Block swizzle: XCD-chunked (bijective, 8 XCDs x 64 blocks) + expert-sorted utterance order
// so each XCD's L2 sees ~1-2 distinct experts' weight panels.
template <int K, int N, int BM, int BN, int WM, int WN, bool RELU, typename OutT>
__global__ __launch_bounds__(WM * WN * 64, 2)
void gemm2ph_kernel(const __bf16* __restrict__ Aall, const __bf16* __restrict__ BTall,
                    const float* __restrict__ biasAll, OutT* __restrict__ Call,
                    const int* __restrict__ chosen) {
  constexpr int THREADS = WM * WN * 64;
  constexpr int MF = BM / (WM * 16);          // m-frags per wave
  constexpr int NF = BN / (WN * 16);          // n-frags per wave
  constexpr int NTN = N / BN;                 // n-tiles per utterance
  constexpr int TILES = (512 / BM) * NTN;     // tiles per utterance
  constexpr int NT = K / 64;                  // K-tiles
  constexpr int CH = THREADS / 8;             // rows covered per global_load_lds call
  constexpr int CPX = (B_ * TILES) / 8;       // blocks per XCD chunk

  __shared__ __bf16 As[2][BM * 64];
  __shared__ __bf16 Bs[2][BN * 64];
  __shared__ int zmap[B_];

  const int tid = threadIdx.x;

  // XCD-chunked bijective swizzle: consecutive launch ids round-robin XCDs, so give each
  // XCD a contiguous chunk of work ids (all tiles of 4 utterances per XCD).
  const int Lw = (blockIdx.x & 7) * CPX + (blockIdx.x >> 3);
  const int zi = Lw / TILES;
  const int tile = Lw % TILES;

  // expert-sorted utterance order (deterministic rank sort of 32 keys; ~1k ops, once per block)
  if (tid < B_) {
    const int key = chosen[tid] * B_ + tid;
    int r = 0;
    for (int b2 = 0; b2 < B_; ++b2) r += (chosen[b2] * B_ + b2) < key;
    zmap[r] = tid;
  }
  __syncthreads();
  const int b = zmap[zi];
  const int e = chosen[b];

  const __bf16* A  = Aall  + (size_t)b * 512 * K;
  const __bf16* BT = BTall + (size_t)e * N * K;
  const float* bias = biasAll + (size_t)e * N;
  OutT* C = Call + (size_t)b * 512 * N;
  const int m0 = (tile / NTN) * BM;
  const int n0 = (tile % NTN) * BN;

  const int lane = tid & 63;
  const int w    = tid >> 6;
  const int wm = w / WN, wn = w % WN;
  const int l16  = lane & 15;
  const int quad = lane >> 4;
  const int lr8  = lane >> 3;                       // staging row-within-8
  const int qsrc = ((lane & 7) ^ lr8) * 8;          // swizzled source k-offset (lane-pure)
  const int swl  = l16 & 7;                         // read-side row swizzle key

  // per-thread staging source pointers (row = chunk_base + w*8 + lr8, k = qsrc)
  const __bf16* aSrc = A  + (size_t)(m0 + w * 8 + lr8) * K + qsrc;
  const __bf16* bSrc = BT + (size_t)(n0 + w * 8 + lr8) * K + qsrc;

  auto stage = [&](int s, int t) {
    const int k0 = t * 64;
#pragma unroll
    for (int j = 0; j < BM / CH; ++j)
      __builtin_amdgcn_global_load_lds(AS1C(aSrc + (size_t)(j * CH) * K + k0),
                                       AS3(&As[s][(j * CH + w * 8) * 64]), 16, 0, 0);
#pragma unroll
    for (int j = 0; j < BN / CH; ++j)
      __builtin_amdgcn_global_load_lds(AS1C(bSrc + (size_t)(j * CH) * K + k0),
                                       AS3(&Bs[s][(j * CH + w * 8) * 64]), 16, 0, 0);
  };

  f32x4 acc[MF][NF] = {};

  auto compute = [&](int s) {
#pragma unroll
    for (int h = 0; h < 2; ++h) {                   // two k-halves of 32
      const int ls = ((h * 4 + quad) ^ swl) * 8;    // physical slot offset (bf16 elems)
      bf16x8 af[MF], bfr[NF];
#pragma unroll
      for (int i = 0; i < MF; ++i)
        af[i]  = *reinterpret_cast<const bf16x8*>(&As[s][(wm * (MF * 16) + i * 16 + l16) * 64 + ls]);
#pragma unroll
      for (int j = 0; j < NF; ++j)
        bfr[j] = *reinterpret_cast<const bf16x8*>(&Bs[s][(wn * (NF * 16) + j * 16 + l16) * 64 + ls]);
#pragma unroll
      for (int i = 0; i < MF; ++i)
#pragma unroll
        for (int j = 0; j < NF; ++j)
          acc[i][j] = __builtin_amdgcn_mfma_f32_16x16x32_bf16(af[i], bfr[j], acc[i][j], 0, 0, 0);
    }
  };

  // prologue: stage tile 0, wait (syncthreads drains vmcnt), then pipelined main loop
  stage(0, 0);
  __syncthreads();
  int s = 0;
  for (int t = 0; t < NT - 1; ++t) {
    stage(s ^ 1, t + 1);      // issue next-tile loads BEFORE compute (T3 ordering)
    compute(s);               // compiler inserts fine-grained lgkmcnt before MFMA use
    __syncthreads();          // vmcnt(0)+lgkmcnt(0)+barrier: next slot ready, this slot free
    s ^= 1;
  }
  compute(s);                 // epilogue tile: no prefetch, no trailing barrier

  // epilogue: C/D layout col=lane&15, row=quad*4+reg
#pragma unroll
  for (int j = 0; j < NF; ++j) {
    const int gn = n0 + wn * (NF * 16) + j * 16 + l16;
    const float bv = bias[gn];
#pragma unroll
    for (int i = 0; i < MF; ++i) {
      const int gm = m0 + wm * (MF * 16) + i * 16 + quad * 4;
#pragma unroll
      for (int r = 0; r < 4; ++r) {
        float v = acc[i][j][r] + bv;
        if (RELU) v = fmaxf(v, 0.f);
        C[(size_t)(gm + r) * N + gn] = (OutT)v;
      }
    }
  }
}

extern "C" void kernel_launch(void* const* d_in, const int* in_sizes, int n_in,
                              void* d_out, int out_size, void* d_ws, size_t ws_size,
                              hipStream_t stream) {
  const float* x  = (const float*)d_in[0];
  const float* Wp = (const float*)d_in[1];
  const float* bp = (const float*)d_in[2];
  const float* W1 = (const float*)d_in[3];
  const float* b1 = (const float*)d_in[4];
  const float* W2 = (const float*)d_in[5];
  const float* b2 = (const float*)d_in[6];
  float* out = (float*)d_out;

  char* ws = (char*)d_ws;
  int*    chosen = (int*)ws;
  __bf16* xbf  = (__bf16*)(ws + 256);                          // 16 MB
  __bf16* w1t  = (__bf16*)(ws + 256 + (size_t)16777216);       // 16 MB  [E,H,D]
  __bf16* w2t  = (__bf16*)(ws + 256 + (size_t)2 * 16777216);   // 16 MB  [E,D,H]
  __bf16* hbuf = (__bf16*)(ws + 256 + (size_t)3 * 16777216);   // 64 MB  [B,T,H]

  float* final_out  = out;                                // [B,T,D]
  float* probs_out  = out + (size_t)B_ * T_ * D_;         // [B,E]
  float* chosen_out = probs_out + B_ * E_;                // [B,1] as float
  float* partial = out;  // [B][P_][D] = 2 MB, consumed by router2 before gemm2 overwrites

  prep_kernel<<<dim3(B_ * S_ + 16 * 256), 256, 0, stream>>>(x, xbf, partial, W1, W2, w1t, w2t);
  router2_kernel<<<B_, 512, 0, stream>>>(partial, Wp, bp, probs_out, chosen_out, chosen);

  // h = relu(x @ W1[e] + b1[e]) : M=512,K=512,N=2048, bf16 out. 256x256 tile, 8 waves,
  // 128 KiB LDS (1 block/CU), 512 blocks = 2 rounds.
  gemm2ph_kernel<512, 2048, 256, 256, 2, 4, true, __bf16>
      <<<dim3(512), 512, 0, stream>>>(xbf, w1t, b1, hbuf, chosen);
  // out = h @ W2[e] + b2[e] : M=512,K=2048,N=512, f32 out. 128x128 tile, 4 waves,
  // 64 KiB LDS (2 blocks/CU co-resident for cross-block overlap), 512 blocks.
  gemm2ph_kernel<2048, 512, 128, 128, 2, 2, false, float>
      <<<dim3(512), 256, 0, stream>>>(hbuf, w2t, b2, final_out, chosen);
}

// Round 2
// 250.925 us; speedup vs baseline: 1.0204x; 1.0204x over previous
//
#include <hip/hip_runtime.h>
#include <cstdint>

#define AS1C(p) ((const __attribute__((address_space(1))) void*)(p))
#define AS3(p)  ((__attribute__((address_space(3))) void*)(p))

typedef __bf16 bf16x8 __attribute__((ext_vector_type(8)));
typedef __bf16 bf16x4 __attribute__((ext_vector_type(4)));
typedef float  f32x4  __attribute__((ext_vector_type(4)));

template <int V> struct Ic { static constexpr int value = V; };

constexpr int B_ = 32, T_ = 512, D_ = 512, E_ = 8, H_ = 2048;
constexpr int S_ = 16;   // pool blocks per utterance
constexpr int P_ = 32;   // partial slots per utterance (2 per pool block)

// ---------------- fused prep: x->bf16 + partial mean-pool, and W1/W2 transpose+cvt ----------------
__global__ __launch_bounds__(256)
void prep_kernel(const float* __restrict__ x, __bf16* __restrict__ xbf,
                 float* __restrict__ partial /*[B][P_][D]*/,
                 const float* __restrict__ W1, const float* __restrict__ W2,
                 __bf16* __restrict__ w1t, __bf16* __restrict__ w2t) {
  __shared__ float t[64][65];
  const int blk = blockIdx.x;
  const int tid = threadIdx.x;
  if (blk < B_ * S_) {
    const int b = blk >> 4, s = blk & 15;
    const int c = (tid & 127) * 4;
    const int half = tid >> 7;
    const size_t base = (size_t)b * T_ * D_ + (size_t)(s * 32) * D_;
    const float* xb = x + base;
    __bf16* ob = xbf + base;
    f32x4 acc = {0.f, 0.f, 0.f, 0.f};
#pragma unroll
    for (int i = 0; i < 16; ++i) {
      const int tr = half + 2 * i;
      f32x4 v = *reinterpret_cast<const f32x4*>(&xb[(size_t)tr * D_ + c]);
      acc += v;
      bf16x4 h; h[0] = (__bf16)v[0]; h[1] = (__bf16)v[1]; h[2] = (__bf16)v[2]; h[3] = (__bf16)v[3];
      *reinterpret_cast<bf16x4*>(&ob[(size_t)tr * D_ + c]) = h;
    }
    float* p = partial + ((size_t)b * P_ + (s * 2 + half)) * D_ + c;
    *reinterpret_cast<f32x4*>(p) = acc;
  } else {
    const int idx = blk - B_ * S_;
    const int z = idx >> 8;
    const int tt = idx & 255;
    const float* src; __bf16* dst; int R, C;
    if (z < E_) { src = W1 + (size_t)z * D_ * H_; dst = w1t + (size_t)z * D_ * H_; R = D_; C = H_; }
    else        { src = W2 + (size_t)(z - E_) * H_ * D_; dst = w2t + (size_t)(z - E_) * H_ * D_; R = H_; C = D_; }
    const int nTc = C >> 6;
    const int c0 = (tt % nTc) * 64;
    const int r0 = (tt / nTc) * 64;
    const int lx = tid & 15, ly = tid >> 4;
#pragma unroll
    for (int i = 0; i < 4; ++i) {
      const int r = ly + i * 16;
      float4 v = *reinterpret_cast<const float4*>(&src[(size_t)(r0 + r) * C + c0 + lx * 4]);
      t[r][lx * 4 + 0] = v.x; t[r][lx * 4 + 1] = v.y;
      t[r][lx * 4 + 2] = v.z; t[r][lx * 4 + 3] = v.w;
    }
    __syncthreads();
#pragma unroll
    for (int h = 0; h < 2; ++h) {
      const int chunk = tid + h * 256;
      const int cc = chunk >> 3;
      const int rr = (chunk & 7) * 8;
      bf16x8 o;
#pragma unroll
      for (int j = 0; j < 8; ++j) o[j] = (__bf16)t[rr + j][cc];
      *reinterpret_cast<bf16x8*>(&dst[(size_t)(c0 + cc) * R + r0 + rr]) = o;
    }
  }
}

// ---------------- router finisher ----------------
__global__ void router2_kernel(const float* __restrict__ partial, const float* __restrict__ Wp,
                               const float* __restrict__ bp, float* __restrict__ probs_out,
                               float* __restrict__ chosen_out_f, int* __restrict__ chosen_ws) {
  const int b = blockIdx.x;
  const int tid = threadIdx.x;  // 512 threads, one per d
  __shared__ float pooled[D_];
  __shared__ float part[E_][64];
  __shared__ float logits[E_];
  const float* p = partial + (size_t)b * P_ * D_;
  float s = 0.f;
#pragma unroll
  for (int i = 0; i < P_; ++i) s += p[i * D_ + tid];
  pooled[tid] = s * (1.0f / (float)T_);
  __syncthreads();
  const int e = tid >> 6, dl = tid & 63;
  float acc = 0.f;
  for (int d = dl; d < D_; d += 64) acc += pooled[d] * Wp[d * E_ + e];
  part[e][dl] = acc;
  __syncthreads();
  if (tid < E_) {
    float sum = bp[tid];
#pragma unroll
    for (int i = 0; i < 64; ++i) sum += part[tid][i];
    logits[tid] = sum;
  }
  __syncthreads();
  if (tid == 0) {
    float mx = logits[0]; int arg = 0;
    for (int i = 1; i < E_; ++i) if (logits[i] > mx) { mx = logits[i]; arg = i; }
    float ex[E_], se = 0.f;
    for (int i = 0; i < E_; ++i) { ex[i] = expf(logits[i] - mx); se += ex[i]; }
    const float inv = 1.0f / se;
    for (int i = 0; i < E_; ++i) probs_out[b * E_ + i] = ex[i] * inv;
    chosen_out_f[b] = (float)arg;
    chosen_ws[b] = arg;
  }
}

// ---------------- batched GEMM, 8-phase counted-vmcnt schedule (m201 port) ----------------
// C[b] = epilogue(A[b] @ BT[e]^T + bias[e]); A:[512,K] k-contig, BT:[N,K] k-contig.
// Per K-tile: 4 quadrant phases (qm,qn) = (0,0)->(0,1)->(1,1)->(1,0) with operand-reuse chain.
// Half-tile ring staging (A_h0/A_h1 = row halves of As[buf], same for Bs): each half of tile
// t+2 is issued exactly one phase after its slot's last read in tile t:
//   ph0 of t: A_h1(t+1), B_h0(t+1) (other buffer, slots last read ph3/ph3 of t-1)
//   ph2 of t: A_h0(t+2)            (slot last read ph1 of t)
//   ph3 of t: B_h1(t+2)            (slot last read ph2 of t)
// ONE counted s_waitcnt vmcnt(LA+LB) per K-tile (end of ph3): guarantees all four halves of
// tile t+1 landed (they precede the last LA+LB issues), never drains to 0 in steady state.
// Phase body: {ds_read quadrant frags; stage; s_barrier; lgkmcnt(0); sched_barrier;
// setprio(1); MFMA cluster; setprio(0); [vmcnt]; s_barrier}. All waves issue identical load
// counts -> per-wave vmcnt discipline is uniform; vmcnt+barrier publishes ALL waves' loads.
// LDS swizzle carried over unchanged (slot p of row r holds k-slot p^(r&7); 0 conflicts R0/R1).
template <int K, int N, int BM, int BN, int WM, int WN, bool RELU, typename OutT>
__global__ __launch_bounds__(512, 2)
void gemm8ph_kernel(const __bf16* __restrict__ Aall, const __bf16* __restrict__ BTall,
                    const float* __restrict__ biasAll, OutT* __restrict__ Call,
                    const int* __restrict__ chosen) {
  static_assert(WM * WN == 8, "8 waves");
  constexpr int MF  = BM / (WM * 16);   // m-frags per wave
  constexpr int NF  = BN / (WN * 16);   // n-frags per wave
  constexpr int MFH = MF / 2, NFH = NF / 2;
  constexpr int NTN = N / BN;
  constexpr int TILES = (512 / BM) * NTN;
  constexpr int NT  = K / 64;           // K-tiles
  constexpr int LA  = BM / 128;         // global_load_lds per A-half (per wave)
  constexpr int LB  = BN / 128;         // per B-half
  constexpr int VSTEADY = LA + LB;
  constexpr int CPX = (B_ * TILES) / 8;

  __shared__ __bf16 As[2][BM * 64];
  __shared__ __bf16 Bs[2][BN * 64];
  __shared__ int zmap[B_];

  const int tid = threadIdx.x;

  // XCD-chunked bijective swizzle (+ expert-sorted utterance order for L2 weight locality)
  const int Lw = (blockIdx.x & 7) * CPX + (blockIdx.x >> 3);
  const int zi = Lw / TILES;
  const int tile = Lw % TILES;
  if (tid < B_) {
    const int key = chosen[tid] * B_ + tid;
    int r = 0;
    for (int b2 = 0; b2 < B_; ++b2) r += (chosen[b2] * B_ + b2) < key;
    zmap[r] = tid;
  }
  __syncthreads();
  const int b = zmap[zi];
  const int e = chosen[b];

  const __bf16* A  = Aall  + (size_t)b * 512 * K;
  const __bf16* BT = BTall + (size_t)e * N * K;
  const float* bias = biasAll + (size_t)e * N;
  OutT* C = Call + (size_t)b * 512 * N;
  const int m0 = (tile / NTN) * BM;
  const int n0 = (tile % NTN) * BN;

  const int lane = tid & 63;
  const int w    = tid >> 6;
  const int wm = w / WN, wn = w % WN;
  const int l16  = lane & 15;
  const int quad = lane >> 4;
  const int lr8  = lane >> 3;
  const int qsrc = ((lane & 7) ^ lr8) * 8;   // swizzled source k-offset (lane-pure)
  const int swl  = l16 & 7;                  // read-side row swizzle key

  // ---- staging: one call covers 64 rows (512 thr x 16 B); halves are BM/2 (BN/2) rows ----
  auto stageA = [&](int s, int t, int h) {
#pragma unroll
    for (int c = 0; c < LA; ++c) {
      const int rbase = h * (BM / 2) + c * 64;
      __builtin_amdgcn_global_load_lds(
          AS1C(A + (size_t)(m0 + rbase + w * 8 + lr8) * K + t * 64 + qsrc),
          AS3(&As[s][(rbase + w * 8) * 64]), 16, 0, 0);
    }
  };
  auto stageB = [&](int s, int t, int h) {
#pragma unroll
    for (int c = 0; c < LB; ++c) {
      const int rbase = h * (BN / 2) + c * 64;
      __builtin_amdgcn_global_load_lds(
          AS1C(BT + (size_t)(n0 + rbase + w * 8 + lr8) * K + t * 64 + qsrc),
          AS3(&Bs[s][(rbase + w * 8) * 64]), 16, 0, 0);
    }
  };

  bf16x8 af[2][MFH], bfr[2][NFH];
  f32x4 acc[MF][NF] = {};

  // quadrant fragment loads: rows(wm,f) = wm*(BM/2/WM) + qm*(BM/2) + f*16 (+l16); same for cols
  auto loadA = [&](int s, int qm) {
#pragma unroll
    for (int h = 0; h < 2; ++h) {
      const int ls = ((h * 4 + quad) ^ swl) * 8;
#pragma unroll
      for (int i = 0; i < MFH; ++i) {
        const int row = wm * (BM / 2 / WM) + qm * (BM / 2) + i * 16 + l16;
        af[h][i] = *reinterpret_cast<const bf16x8*>(&As[s][row * 64 + ls]);
      }
    }
  };
  auto loadB = [&](int s, int qn) {
#pragma unroll
    for (int h = 0; h < 2; ++h) {
      const int ls = ((h * 4 + quad) ^ swl) * 8;
#pragma unroll
      for (int j = 0; j < NFH; ++j) {
        const int row = wn * (BN / 2 / WN) + qn * (BN / 2) + j * 16 + l16;
        bfr[h][j] = *reinterpret_cast<const bf16x8*>(&Bs[s][row * 64 + ls]);
      }
    }
  };

  // phase tail: barrier; lgkm(0); MFMA quadrant; [vmcnt]; barrier.  vm: -1 none, 0 drain, 1 steady
  auto phase = [&](auto qmC, auto qnC, int vm) {
    constexpr int QM = decltype(qmC)::value, QN = decltype(qnC)::value;
    __builtin_amdgcn_s_barrier();
    asm volatile("s_waitcnt lgkmcnt(0)" ::: "memory");
    __builtin_amdgcn_sched_barrier(0);
    __builtin_amdgcn_s_setprio(1);
#pragma unroll
    for (int h = 0; h < 2; ++h)
#pragma unroll
      for (int i = 0; i < MFH; ++i)
#pragma unroll
        for (int j = 0; j < NFH; ++j)
          acc[QM * MFH + i][QN * NFH + j] = __builtin_amdgcn_mfma_f32_16x16x32_bf16(
              af[h][i], bfr[h][j], acc[QM * MFH + i][QN * NFH + j], 0, 0, 0);
    __builtin_amdgcn_s_setprio(0);
    if (vm == 0)      asm volatile("s_waitcnt vmcnt(0)" ::: "memory");
    else if (vm > 0)  asm volatile("s_waitcnt vmcnt(%0)" :: "n"(VSTEADY) : "memory");
    __builtin_amdgcn_s_barrier();
  };

  // ---- prologue: tile0 fully + tile1's {A_h0, B_h1}; counted wait leaves only those in flight
  stageA(0, 0, 0); stageB(0, 0, 0); stageB(0, 0, 1); stageA(0, 0, 1);
  if (NT > 1) { stageA(1, 1, 0); stageB(1, 1, 1); }
  if (NT > 1) asm volatile("s_waitcnt vmcnt(%0)" :: "n"(VSTEADY) : "memory");
  else        asm volatile("s_waitcnt vmcnt(0)" ::: "memory");
  __builtin_amdgcn_s_barrier();

  for (int t = 0; t < NT; ++t) {
    const int s = t & 1, so = s ^ 1;
    const int vm = (t + 1 >= NT) ? -1 : ((t + 2 >= NT) ? 0 : 1);
    // phase 0: (qm=0, qn=0)
    loadA(s, 0); loadB(s, 0);
    if (t + 1 < NT) { stageA(so, t + 1, 1); stageB(so, t + 1, 0); }
    phase(Ic<0>{}, Ic<0>{}, -1);
    // phase 1: (0,1) — A reused
    loadB(s, 1);
    phase(Ic<0>{}, Ic<1>{}, -1);
    // phase 2: (1,1) — B reused
    loadA(s, 1);
    if (t + 2 < NT) stageA(s, t + 2, 0);
    phase(Ic<1>{}, Ic<1>{}, -1);
    // phase 3: (1,0) — A reused, B_h0 re-read
    loadB(s, 0);
    if (t + 2 < NT) stageB(s, t + 2, 1);
    phase(Ic<1>{}, Ic<0>{}, vm);
  }

  // ---- epilogue: C/D layout col=lane&15, row=quad*4+reg; j-pairs adjacent in time ----
  float bv[NF];
#pragma unroll
  for (int j = 0; j < NF; ++j)
    bv[j] = bias[n0 + wn * (BN / 2 / WN) + (j / NFH) * (BN / 2) + (j % NFH) * 16 + l16];
#pragma unroll
  for (int i = 0; i < MF; ++i) {
    const int gm = m0 + wm * (BM / 2 / WM) + (i / MFH) * (BM / 2) + (i % MFH) * 16 + quad * 4;
#pragma unroll
    for (int r = 0; r < 4; ++r) {
      OutT* Crow = C + (size_t)(gm + r) * N;
#pragma unroll
      for (int j = 0; j < NF; ++j) {
        const int gn = n0 + wn * (BN / 2 / WN) + (j / NFH) * (BN / 2) + (j % NFH) * 16 + l16;
        float v = acc[i][j][r] + bv[j];
        if (RELU) v = fmaxf(v, 0.f);
        Crow[gn] = (OutT)v;
      }
    }
  }
}

extern "C" void kernel_launch(void* const* d_in, const int* in_sizes, int n_in,
                              void* d_out, int out_size, void* d_ws, size_t ws_size,
                              hipStream_t stream) {
  const float* x  = (const float*)d_in[0];
  const float* Wp = (const float*)d_in[1];
  const float* bp = (const float*)d_in[2];
  const float* W1 = (const float*)d_in[3];
  const float* b1 = (const float*)d_in[4];
  const float* W2 = (const float*)d_in[5];
  const float* b2 = (const float*)d_in[6];
  float* out = (float*)d_out;

  char* ws = (char*)d_ws;
  int*    chosen = (int*)ws;
  __bf16* xbf  = (__bf16*)(ws + 256);                          // 16 MB
  __bf16* w1t  = (__bf16*)(ws + 256 + (size_t)16777216);       // 16 MB  [E,H,D]
  __bf16* w2t  = (__bf16*)(ws + 256 + (size_t)2 * 16777216);   // 16 MB  [E,D,H]
  __bf16* hbuf = (__bf16*)(ws + 256 + (size_t)3 * 16777216);   // 64 MB  [B,T,H]

  float* final_out  = out;                                // [B,T,D]
  float* probs_out  = out + (size_t)B_ * T_ * D_;         // [B,E]
  float* chosen_out = probs_out + B_ * E_;                // [B,1] as float
  float* partial = out;  // [B][P_][D] = 2 MB, consumed by router2 before gemm2 overwrites

  prep_kernel<<<dim3(B_ * S_ + 16 * 256), 256, 0, stream>>>(x, xbf, partial, W1, W2, w1t, w2t);
  router2_kernel<<<B_, 512, 0, stream>>>(partial, Wp, bp, probs_out, chosen_out, chosen);

  // h = relu(x @ W1[e] + b1[e]) : M=512,K=512,N=2048. 256x256, 2x4 waves, 128 KiB LDS,
  // 512 blocks (2 rounds of 256 CUs).
  gemm8ph_kernel<512, 2048, 256, 256, 2, 4, true, __bf16>
      <<<dim3(512), 512, 0, stream>>>(xbf, w1t, b1, hbuf, chosen);
  // out = h @ W2[e] + b2[e] : M=512,K=2048,N=512. 256x128, 4x2 waves, 96 KiB LDS,
  // 256 blocks = exactly 1/CU.
  gemm8ph_kernel<2048, 512, 256, 128, 4, 2, false, float>
      <<<dim3(256), 512, 0, stream>>>(hbuf, w2t, b2, final_out, chosen);
}

// Round 3
// 241.673 us; speedup vs baseline: 1.0595x; 1.0383x over previous
//
#include <hip/hip_runtime.h>
#include <cstdint>

#define AS1C(p) ((const __attribute__((address_space(1))) void*)(p))
#define AS3(p)  ((__attribute__((address_space(3))) void*)(p))

typedef __bf16 bf16x8 __attribute__((ext_vector_type(8)));
typedef __bf16 bf16x4 __attribute__((ext_vector_type(4)));
typedef float  f32x4  __attribute__((ext_vector_type(4)));

template <int V> struct Ic { static constexpr int value = V; };

constexpr int B_ = 32, T_ = 512, D_ = 512, E_ = 8, H_ = 2048;
constexpr int S_ = 16;   // pool blocks per utterance
constexpr int P_ = 32;   // partial slots per utterance (2 per pool block)

// ---------------- fused prep: x->bf16 + partial mean-pool, and W1/W2 transpose+cvt ----------------
__global__ __launch_bounds__(256)
void prep_kernel(const float* __restrict__ x, __bf16* __restrict__ xbf,
                 float* __restrict__ partial /*[B][P_][D]*/,
                 const float* __restrict__ W1, const float* __restrict__ W2,
                 __bf16* __restrict__ w1t, __bf16* __restrict__ w2t) {
  __shared__ float t[64][65];
  const int blk = blockIdx.x;
  const int tid = threadIdx.x;
  if (blk < B_ * S_) {
    const int b = blk >> 4, s = blk & 15;
    const int c = (tid & 127) * 4;
    const int half = tid >> 7;
    const size_t base = (size_t)b * T_ * D_ + (size_t)(s * 32) * D_;
    const float* xb = x + base;
    __bf16* ob = xbf + base;
    f32x4 acc = {0.f, 0.f, 0.f, 0.f};
#pragma unroll
    for (int i = 0; i < 16; ++i) {
      const int tr = half + 2 * i;
      f32x4 v = *reinterpret_cast<const f32x4*>(&xb[(size_t)tr * D_ + c]);
      acc += v;
      bf16x4 h; h[0] = (__bf16)v[0]; h[1] = (__bf16)v[1]; h[2] = (__bf16)v[2]; h[3] = (__bf16)v[3];
      *reinterpret_cast<bf16x4*>(&ob[(size_t)tr * D_ + c]) = h;
    }
    float* p = partial + ((size_t)b * P_ + (s * 2 + half)) * D_ + c;
    *reinterpret_cast<f32x4*>(p) = acc;
  } else {
    const int idx = blk - B_ * S_;
    const int z = idx >> 8;
    const int tt = idx & 255;
    const float* src; __bf16* dst; int R, C;
    if (z < E_) { src = W1 + (size_t)z * D_ * H_; dst = w1t + (size_t)z * D_ * H_; R = D_; C = H_; }
    else        { src = W2 + (size_t)(z - E_) * H_ * D_; dst = w2t + (size_t)(z - E_) * H_ * D_; R = H_; C = D_; }
    const int nTc = C >> 6;
    const int c0 = (tt % nTc) * 64;
    const int r0 = (tt / nTc) * 64;
    const int lx = tid & 15, ly = tid >> 4;
#pragma unroll
    for (int i = 0; i < 4; ++i) {
      const int r = ly + i * 16;
      float4 v = *reinterpret_cast<const float4*>(&src[(size_t)(r0 + r) * C + c0 + lx * 4]);
      t[r][lx * 4 + 0] = v.x; t[r][lx * 4 + 1] = v.y;
      t[r][lx * 4 + 2] = v.z; t[r][lx * 4 + 3] = v.w;
    }
    __syncthreads();
#pragma unroll
    for (int h = 0; h < 2; ++h) {
      const int chunk = tid + h * 256;
      const int cc = chunk >> 3;
      const int rr = (chunk & 7) * 8;
      bf16x8 o;
#pragma unroll
      for (int j = 0; j < 8; ++j) o[j] = (__bf16)t[rr + j][cc];
      *reinterpret_cast<bf16x8*>(&dst[(size_t)(c0 + cc) * R + r0 + rr]) = o;
    }
  }
}

// ---------------- router finisher ----------------
__global__ void router2_kernel(const float* __restrict__ partial, const float* __restrict__ Wp,
                               const float* __restrict__ bp, float* __restrict__ probs_out,
                               float* __restrict__ chosen_out_f, int* __restrict__ chosen_ws) {
  const int b = blockIdx.x;
  const int tid = threadIdx.x;  // 512 threads, one per d
  __shared__ float pooled[D_];
  __shared__ float part[E_][64];
  __shared__ float logits[E_];
  const float* p = partial + (size_t)b * P_ * D_;
  float s = 0.f;
#pragma unroll
  for (int i = 0; i < P_; ++i) s += p[i * D_ + tid];
  pooled[tid] = s * (1.0f / (float)T_);
  __syncthreads();
  const int e = tid >> 6, dl = tid & 63;
  float acc = 0.f;
  for (int d = dl; d < D_; d += 64) acc += pooled[d] * Wp[d * E_ + e];
  part[e][dl] = acc;
  __syncthreads();
  if (tid < E_) {
    float sum = bp[tid];
#pragma unroll
    for (int i = 0; i < 64; ++i) sum += part[tid][i];
    logits[tid] = sum;
  }
  __syncthreads();
  if (tid == 0) {
    float mx = logits[0]; int arg = 0;
    for (int i = 1; i < E_; ++i) if (logits[i] > mx) { mx = logits[i]; arg = i; }
    float ex[E_], se = 0.f;
    for (int i = 0; i < E_; ++i) { ex[i] = expf(logits[i] - mx); se += ex[i]; }
    const float inv = 1.0f / se;
    for (int i = 0; i < E_; ++i) probs_out[b * E_ + i] = ex[i] * inv;
    chosen_out_f[b] = (float)arg;
    chosen_ws[b] = arg;
  }
}

// ---------------- gemm1: h = relu(x @ W1[e] + b1[e])  M=512,K=512,N=2048 ----------------
// m201-geometry (256x256, 2x4 waves, per-wave 128x64, 16 MFMA/phase, counted vmcnt(4) ring).
// NEW: epilogue LDS-bounce — acc is scattered per-lane (2B stride-16 cols); direct bf16 stores
// measured 4.2x HBM write-amp (R1: WRITE 140MB for 33.5MB logical). Bounce: each wave writes
// its 128x64 C-subtile into a private 16KB LDS region (XOR row-swizzle for bank spread),
// reads back b128 rows, stores coalesced bf16x8 (full 64B sectors).
__global__ __launch_bounds__(512, 2)
void gemm1_kernel(const __bf16* __restrict__ Aall, const __bf16* __restrict__ BTall,
                  const float* __restrict__ biasAll, __bf16* __restrict__ Call,
                  const int* __restrict__ chosen) {
  constexpr int K = 512, N = 2048, BM = 256, BN = 256, WM = 2, WN = 4;
  constexpr int MF = 8, NF = 4, MFH = 4, NFH = 2;
  constexpr int NTN = N / BN;             // 8
  constexpr int TILES = (512 / BM) * NTN; // 16
  constexpr int NT = K / 64;              // 8
  constexpr int LA = BM / 128, LB = BN / 128;  // 2,2
  constexpr int VSTEADY = LA + LB;        // 4
  constexpr int CPX = (B_ * TILES) / 8;   // 64

  __shared__ __bf16 As[2][BM * 64];
  __shared__ __bf16 Bs[2][BN * 64];
  __shared__ int zmap[B_];

  const int tid = threadIdx.x;
  const int Lw = (blockIdx.x & 7) * CPX + (blockIdx.x >> 3);
  const int zi = Lw / TILES, tile = Lw % TILES;
  if (tid < B_) {
    const int key = chosen[tid] * B_ + tid;
    int r = 0;
    for (int b2 = 0; b2 < B_; ++b2) r += (chosen[b2] * B_ + b2) < key;
    zmap[r] = tid;
  }
  __syncthreads();
  const int b = zmap[zi];
  const int e = chosen[b];

  const __bf16* A  = Aall  + (size_t)b * 512 * K;
  const __bf16* BT = BTall + (size_t)e * N * K;
  const float* bias = biasAll + (size_t)e * N;
  __bf16* C = Call + (size_t)b * 512 * N;
  const int m0 = (tile / NTN) * BM;
  const int n0 = (tile % NTN) * BN;

  const int lane = tid & 63;
  const int w    = tid >> 6;
  const int wm = w / WN, wn = w % WN;
  const int l16  = lane & 15;
  const int quad = lane >> 4;
  const int lr8  = lane >> 3;
  const int qsrc = ((lane & 7) ^ lr8) * 8;
  const int swl  = l16 & 7;

  auto stageA = [&](int s, int t, int h) {
#pragma unroll
    for (int c = 0; c < LA; ++c) {
      const int rbase = h * (BM / 2) + c * 64;
      __builtin_amdgcn_global_load_lds(
          AS1C(A + (size_t)(m0 + rbase + w * 8 + lr8) * K + t * 64 + qsrc),
          AS3(&As[s][(rbase + w * 8) * 64]), 16, 0, 0);
    }
  };
  auto stageB = [&](int s, int t, int h) {
#pragma unroll
    for (int c = 0; c < LB; ++c) {
      const int rbase = h * (BN / 2) + c * 64;
      __builtin_amdgcn_global_load_lds(
          AS1C(BT + (size_t)(n0 + rbase + w * 8 + lr8) * K + t * 64 + qsrc),
          AS3(&Bs[s][(rbase + w * 8) * 64]), 16, 0, 0);
    }
  };

  bf16x8 af[2][MFH], bfr[2][NFH];
  f32x4 acc[MF][NF] = {};

  auto loadA = [&](int s, int qm) {
#pragma unroll
    for (int h = 0; h < 2; ++h) {
      const int ls = ((h * 4 + quad) ^ swl) * 8;
#pragma unroll
      for (int i = 0; i < MFH; ++i) {
        const int row = wm * (BM / 2 / WM) + qm * (BM / 2) + i * 16 + l16;
        af[h][i] = *reinterpret_cast<const bf16x8*>(&As[s][row * 64 + ls]);
      }
    }
  };
  auto loadB = [&](int s, int qn) {
#pragma unroll
    for (int h = 0; h < 2; ++h) {
      const int ls = ((h * 4 + quad) ^ swl) * 8;
#pragma unroll
      for (int j = 0; j < NFH; ++j) {
        const int row = wn * (BN / 2 / WN) + qn * (BN / 2) + j * 16 + l16;
        bfr[h][j] = *reinterpret_cast<const bf16x8*>(&Bs[s][row * 64 + ls]);
      }
    }
  };

  auto phase = [&](auto qmC, auto qnC, int vm) {
    constexpr int QM = decltype(qmC)::value, QN = decltype(qnC)::value;
    __builtin_amdgcn_s_barrier();
    asm volatile("s_waitcnt lgkmcnt(0)" ::: "memory");
    __builtin_amdgcn_sched_barrier(0);
    __builtin_amdgcn_s_setprio(1);
#pragma unroll
    for (int h = 0; h < 2; ++h)
#pragma unroll
      for (int i = 0; i < MFH; ++i)
#pragma unroll
        for (int j = 0; j < NFH; ++j)
          acc[QM * MFH + i][QN * NFH + j] = __builtin_amdgcn_mfma_f32_16x16x32_bf16(
              af[h][i], bfr[h][j], acc[QM * MFH + i][QN * NFH + j], 0, 0, 0);
    __builtin_amdgcn_s_setprio(0);
    if (vm == 0)      asm volatile("s_waitcnt vmcnt(0)" ::: "memory");
    else if (vm > 0)  asm volatile("s_waitcnt vmcnt(%0)" :: "n"(VSTEADY) : "memory");
    __builtin_amdgcn_s_barrier();
  };

  // prologue: tile0 fully + tile1's {A_h0, B_h1}
  stageA(0, 0, 0); stageB(0, 0, 0); stageB(0, 0, 1); stageA(0, 0, 1);
  stageA(1, 1, 0); stageB(1, 1, 1);
  asm volatile("s_waitcnt vmcnt(%0)" :: "n"(VSTEADY) : "memory");
  __builtin_amdgcn_s_barrier();

  for (int t = 0; t < NT; ++t) {
    const int s = t & 1, so = s ^ 1;
    const int vm = (t + 1 >= NT) ? -1 : ((t + 2 >= NT) ? 0 : 1);
    loadA(s, 0); loadB(s, 0);
    if (t + 1 < NT) { stageA(so, t + 1, 1); stageB(so, t + 1, 0); }
    phase(Ic<0>{}, Ic<0>{}, -1);
    loadB(s, 1);
    phase(Ic<0>{}, Ic<1>{}, -1);
    loadA(s, 1);
    if (t + 2 < NT) stageA(s, t + 2, 0);
    phase(Ic<1>{}, Ic<1>{}, -1);
    loadB(s, 0);
    if (t + 2 < NT) stageB(s, t + 2, 1);
    phase(Ic<1>{}, Ic<0>{}, vm);
  }

  // ---- LDS-bounce epilogue: per-wave private 16KB region (no barrier needed) ----
  // write: local row L = i*16 + quad*4 + r (0..127), local col c = j*16 + l16 (0..63),
  // phys = L*64 + (c ^ ((L&7)<<3)).  readback: 16x b128 rows; logical chunk = p^(L&7).
  __bf16* wl = (w < 4) ? (&As[0][0] + w * 8192) : (&Bs[0][0] + (w - 4) * 8192);
  float bv[NF];
#pragma unroll
  for (int j = 0; j < NF; ++j)
    bv[j] = bias[n0 + wn * (BN / 2 / WN) + (j / NFH) * (BN / 2) + (j % NFH) * 16 + l16];
#pragma unroll
  for (int i = 0; i < MF; ++i)
#pragma unroll
    for (int r = 0; r < 4; ++r) {
      const int L = i * 16 + quad * 4 + r;
      const int key = (L & 7) << 3;
#pragma unroll
      for (int j = 0; j < NF; ++j) {
        float v = fmaxf(acc[i][j][r] + bv[j], 0.f);   // relu
        wl[L * 64 + ((j * 16 + l16) ^ key)] = (__bf16)v;
      }
    }
#pragma unroll
  for (int it = 0; it < 16; ++it) {
    const int L = it * 8 + (lane >> 3);
    const int p = lane & 7;
    bf16x8 vrow = *reinterpret_cast<const bf16x8*>(&wl[L * 64 + p * 8]);
    const int lc = (p ^ (L & 7)) * 8;
    const int i = L >> 4, qr = L & 15;
    const int j = lc >> 4, cl = lc & 15;
    const int gm = m0 + wm * (BM / 2 / WM) + (i / MFH) * (BM / 2) + (i % MFH) * 16 + qr;
    const int gn = n0 + wn * (BN / 2 / WN) + (j / NFH) * (BN / 2) + (j % NFH) * 16 + cl;
    *reinterpret_cast<bf16x8*>(&C[(size_t)gm * N + gn]) = vrow;
  }
}

// ---------------- gemm2: out = h @ W2[e] + b2[e]  M=512,K=2048,N=512 ----------------
// 256x128 tile, 4x2 waves (per-wave 64x64), 256 blocks = 1/CU.
// 2 LDS-phases per K-tile (m-half split): 16 MFMA per barrier-pair (m201-sized clusters),
// hold-all-B in registers (16 b128/wave/tile = minimum), 4 barriers/tile (was 8).
// Triple-buffered whole-tile staging (144KB LDS): stage t+2 at ph0(t); counted vmcnt(6) at
// ph1(t) guarantees tile t+1 landed (cover ~4 phases); drains to 0 only at the final tiles.
__global__ __launch_bounds__(512, 2)
void gemm2_kernel(const __bf16* __restrict__ Aall, const __bf16* __restrict__ BTall,
                  const float* __restrict__ biasAll, float* __restrict__ Call,
                  const int* __restrict__ chosen) {
  constexpr int K = 2048, N = 512, BM = 256, BN = 128;
  constexpr int NT = K / 64;            // 32
  constexpr int TILES = 8;              // (512/256)*(512/128)
  constexpr int CPX = (B_ * TILES) / 8; // 32

  __shared__ __bf16 As[3][BM * 64];     // 96 KB
  __shared__ __bf16 Bs[3][BN * 64];     // 48 KB
  __shared__ int zmap[B_];

  const int tid = threadIdx.x;
  const int Lw = (blockIdx.x & 7) * CPX + (blockIdx.x >> 3);
  const int zi = Lw / TILES, tile = Lw % TILES;
  if (tid < B_) {
    const int key = chosen[tid] * B_ + tid;
    int r = 0;
    for (int b2 = 0; b2 < B_; ++b2) r += (chosen[b2] * B_ + b2) < key;
    zmap[r] = tid;
  }
  __syncthreads();
  const int b = zmap[zi];
  const int e = chosen[b];

  const __bf16* A  = Aall  + (size_t)b * 512 * K;
  const __bf16* BT = BTall + (size_t)e * N * K;
  const float* bias = biasAll + (size_t)e * N;
  float* C = Call + (size_t)b * 512 * N;
  const int m0 = (tile >> 2) * BM;
  const int n0 = (tile & 3) * BN;

  const int lane = tid & 63;
  const int w    = tid >> 6;
  const int wm = w >> 1, wn = w & 1;    // 4x2 wave grid
  const int l16  = lane & 15;
  const int quad = lane >> 4;
  const int lr8  = lane >> 3;
  const int qsrc = ((lane & 7) ^ lr8) * 8;
  const int swl  = l16 & 7;

  const __bf16* aSrc = A  + (size_t)(m0 + w * 8 + lr8) * K + qsrc;
  const __bf16* bSrc = BT + (size_t)(n0 + w * 8 + lr8) * K + qsrc;

  auto stage = [&](int buf, int t) {
#pragma unroll
    for (int c = 0; c < 4; ++c)
      __builtin_amdgcn_global_load_lds(AS1C(aSrc + (size_t)(c * 64) * K + t * 64),
                                       AS3(&As[buf][(c * 64 + w * 8) * 64]), 16, 0, 0);
#pragma unroll
    for (int c = 0; c < 2; ++c)
      __builtin_amdgcn_global_load_lds(AS1C(bSrc + (size_t)(c * 64) * K + t * 64),
                                       AS3(&Bs[buf][(c * 64 + w * 8) * 64]), 16, 0, 0);
  };

  f32x4 acc[4][4] = {};
  bf16x8 af[2][2], bfr[2][4];

  auto loadB_all = [&](int buf) {
#pragma unroll
    for (int h = 0; h < 2; ++h) {
      const int ls = ((h * 4 + quad) ^ swl) * 8;
#pragma unroll
      for (int j = 0; j < 4; ++j)
        bfr[h][j] = *reinterpret_cast<const bf16x8*>(&Bs[buf][(wn * 64 + j * 16 + l16) * 64 + ls]);
    }
  };
  auto loadA_half = [&](int buf, int ih) {
#pragma unroll
    for (int h = 0; h < 2; ++h) {
      const int ls = ((h * 4 + quad) ^ swl) * 8;
#pragma unroll
      for (int ii = 0; ii < 2; ++ii)
        af[h][ii] = *reinterpret_cast<const bf16x8*>(
            &As[buf][(wm * 64 + (ih * 2 + ii) * 16 + l16) * 64 + ls]);
    }
  };
  auto mfma_half = [&](auto ihC) {
    constexpr int IH = decltype(ihC)::value;
#pragma unroll
    for (int h = 0; h < 2; ++h)
#pragma unroll
      for (int ii = 0; ii < 2; ++ii)
#pragma unroll
        for (int j = 0; j < 4; ++j)
          acc[IH * 2 + ii][j] = __builtin_amdgcn_mfma_f32_16x16x32_bf16(
              af[h][ii], bfr[h][j], acc[IH * 2 + ii][j], 0, 0, 0);
  };

  // prologue: stage tiles 0,1; counted wait leaves tile1's 6 loads in flight
  stage(0, 0); stage(1, 1);
  asm volatile("s_waitcnt vmcnt(6)" ::: "memory");
  __builtin_amdgcn_s_barrier();

  for (int t = 0; t < NT; ++t) {
    const int cur = t % 3;
    // phase 0: all-B + A m-half0; stage tile t+2 into free buffer
    loadB_all(cur);
    loadA_half(cur, 0);
    if (t + 2 < NT) stage((t + 2) % 3, t + 2);
    __builtin_amdgcn_s_barrier();
    asm volatile("s_waitcnt lgkmcnt(0)" ::: "memory");
    __builtin_amdgcn_sched_barrier(0);
    __builtin_amdgcn_s_setprio(1);
    mfma_half(Ic<0>{});
    __builtin_amdgcn_s_setprio(0);
    __builtin_amdgcn_s_barrier();
    // phase 1: A m-half1 (B held in regs)
    loadA_half(cur, 1);
    __builtin_amdgcn_s_barrier();
    asm volatile("s_waitcnt lgkmcnt(0)" ::: "memory");
    __builtin_amdgcn_sched_barrier(0);
    __builtin_amdgcn_s_setprio(1);
    mfma_half(Ic<1>{});
    __builtin_amdgcn_s_setprio(0);
    if (t + 2 < NT)      asm volatile("s_waitcnt vmcnt(6)" ::: "memory");
    else if (t + 1 < NT) asm volatile("s_waitcnt vmcnt(0)" ::: "memory");
    __builtin_amdgcn_s_barrier();
  }

  // epilogue: f32 stores, 16 lanes x 4B = 64B sectors (no write amp)
  float bv[4];
#pragma unroll
  for (int j = 0; j < 4; ++j) bv[j] = bias[n0 + wn * 64 + j * 16 + l16];
#pragma unroll
  for (int i = 0; i < 4; ++i) {
    const int gm = m0 + wm * 64 + i * 16 + quad * 4;
#pragma unroll
    for (int r = 0; r < 4; ++r) {
      float* Crow = C + (size_t)(gm + r) * N;
#pragma unroll
      for (int j = 0; j < 4; ++j)
        Crow[n0 + wn * 64 + j * 16 + l16] = acc[i][j][r] + bv[j];
    }
  }
}

extern "C" void kernel_launch(void* const* d_in, const int* in_sizes, int n_in,
                              void* d_out, int out_size, void* d_ws, size_t ws_size,
                              hipStream_t stream) {
  const float* x  = (const float*)d_in[0];
  const float* Wp = (const float*)d_in[1];
  const float* bp = (const float*)d_in[2];
  const float* W1 = (const float*)d_in[3];
  const float* b1 = (const float*)d_in[4];
  const float* W2 = (const float*)d_in[5];
  const float* b2 = (const float*)d_in[6];
  float* out = (float*)d_out;

  char* ws = (char*)d_ws;
  int*    chosen = (int*)ws;
  __bf16* xbf  = (__bf16*)(ws + 256);                          // 16 MB
  __bf16* w1t  = (__bf16*)(ws + 256 + (size_t)16777216);       // 16 MB  [E,H,D]
  __bf16* w2t  = (__bf16*)(ws + 256 + (size_t)2 * 16777216);   // 16 MB  [E,D,H]
  __bf16* hbuf = (__bf16*)(ws + 256 + (size_t)3 * 16777216);   // 64 MB  [B,T,H]

  float* final_out  = out;                                // [B,T,D]
  float* probs_out  = out + (size_t)B_ * T_ * D_;         // [B,E]
  float* chosen_out = probs_out + B_ * E_;                // [B,1] as float
  float* partial = out;  // [B][P_][D] = 2 MB, consumed by router2 before gemm2 overwrites

  prep_kernel<<<dim3(B_ * S_ + 16 * 256), 256, 0, stream>>>(x, xbf, partial, W1, W2, w1t, w2t);
  router2_kernel<<<B_, 512, 0, stream>>>(partial, Wp, bp, probs_out, chosen_out, chosen);

  gemm1_kernel<<<dim3(512), 512, 0, stream>>>(xbf, w1t, b1, hbuf, chosen);
  gemm2_kernel<<<dim3(256), 512, 0, stream>>>(hbuf, w2t, b2, final_out, chosen);
}

// Round 4
// 241.408 us; speedup vs baseline: 1.0606x; 1.0011x over previous
//
#include <hip/hip_runtime.h>
#include <cstdint>

#define AS1C(p) ((const __attribute__((address_space(1))) void*)(p))
#define AS3(p)  ((__attribute__((address_space(3))) void*)(p))

typedef __bf16 bf16x8 __attribute__((ext_vector_type(8)));
typedef __bf16 bf16x4 __attribute__((ext_vector_type(4)));
typedef float  f32x4  __attribute__((ext_vector_type(4)));

constexpr int B_ = 32, T_ = 512, D_ = 512, E_ = 8, H_ = 2048;
constexpr int S_ = 16;   // pool blocks per utterance
constexpr int P_ = 32;   // partial slots per utterance (2 per pool block)

// ---------------- fused prep: x->bf16 + partial mean-pool, and W1/W2 transpose+cvt ----------------
__global__ __launch_bounds__(256)
void prep_kernel(const float* __restrict__ x, __bf16* __restrict__ xbf,
                 float* __restrict__ partial /*[B][P_][D]*/,
                 const float* __restrict__ W1, const float* __restrict__ W2,
                 __bf16* __restrict__ w1t, __bf16* __restrict__ w2t) {
  __shared__ float t[64][65];
  const int blk = blockIdx.x;
  const int tid = threadIdx.x;
  if (blk < B_ * S_) {
    const int b = blk >> 4, s = blk & 15;
    const int c = (tid & 127) * 4;
    const int half = tid >> 7;
    const size_t base = (size_t)b * T_ * D_ + (size_t)(s * 32) * D_;
    const float* xb = x + base;
    __bf16* ob = xbf + base;
    f32x4 acc = {0.f, 0.f, 0.f, 0.f};
#pragma unroll
    for (int i = 0; i < 16; ++i) {
      const int tr = half + 2 * i;
      f32x4 v = *reinterpret_cast<const f32x4*>(&xb[(size_t)tr * D_ + c]);
      acc += v;
      bf16x4 h; h[0] = (__bf16)v[0]; h[1] = (__bf16)v[1]; h[2] = (__bf16)v[2]; h[3] = (__bf16)v[3];
      *reinterpret_cast<bf16x4*>(&ob[(size_t)tr * D_ + c]) = h;
    }
    float* p = partial + ((size_t)b * P_ + (s * 2 + half)) * D_ + c;
    *reinterpret_cast<f32x4*>(p) = acc;
  } else {
    const int idx = blk - B_ * S_;
    const int z = idx >> 8;
    const int tt = idx & 255;
    const float* src; __bf16* dst; int R, C;
    if (z < E_) { src = W1 + (size_t)z * D_ * H_; dst = w1t + (size_t)z * D_ * H_; R = D_; C = H_; }
    else        { src = W2 + (size_t)(z - E_) * H_ * D_; dst = w2t + (size_t)(z - E_) * H_ * D_; R = H_; C = D_; }
    const int nTc = C >> 6;
    const int c0 = (tt % nTc) * 64;
    const int r0 = (tt / nTc) * 64;
    const int lx = tid & 15, ly = tid >> 4;
#pragma unroll
    for (int i = 0; i < 4; ++i) {
      const int r = ly + i * 16;
      float4 v = *reinterpret_cast<const float4*>(&src[(size_t)(r0 + r) * C + c0 + lx * 4]);
      t[r][lx * 4 + 0] = v.x; t[r][lx * 4 + 1] = v.y;
      t[r][lx * 4 + 2] = v.z; t[r][lx * 4 + 3] = v.w;
    }
    __syncthreads();
#pragma unroll
    for (int h = 0; h < 2; ++h) {
      const int chunk = tid + h * 256;
      const int cc = chunk >> 3;
      const int rr = (chunk & 7) * 8;
      bf16x8 o;
#pragma unroll
      for (int j = 0; j < 8; ++j) o[j] = (__bf16)t[rr + j][cc];
      *reinterpret_cast<bf16x8*>(&dst[(size_t)(c0 + cc) * R + r0 + rr]) = o;
    }
  }
}

// ---------------- router finisher ----------------
__global__ void router2_kernel(const float* __restrict__ partial, const float* __restrict__ Wp,
                               const float* __restrict__ bp, float* __restrict__ probs_out,
                               float* __restrict__ chosen_out_f, int* __restrict__ chosen_ws) {
  const int b = blockIdx.x;
  const int tid = threadIdx.x;  // 512 threads, one per d
  __shared__ float pooled[D_];
  __shared__ float part[E_][64];
  __shared__ float logits[E_];
  const float* p = partial + (size_t)b * P_ * D_;
  float s = 0.f;
#pragma unroll
  for (int i = 0; i < P_; ++i) s += p[i * D_ + tid];
  pooled[tid] = s * (1.0f / (float)T_);
  __syncthreads();
  const int e = tid >> 6, dl = tid & 63;
  float acc = 0.f;
  for (int d = dl; d < D_; d += 64) acc += pooled[d] * Wp[d * E_ + e];
  part[e][dl] = acc;
  __syncthreads();
  if (tid < E_) {
    float sum = bp[tid];
#pragma unroll
    for (int i = 0; i < 64; ++i) sum += part[tid][i];
    logits[tid] = sum;
  }
  __syncthreads();
  if (tid == 0) {
    float mx = logits[0]; int arg = 0;
    for (int i = 1; i < E_; ++i) if (logits[i] > mx) { mx = logits[i]; arg = i; }
    float ex[E_], se = 0.f;
    for (int i = 0; i < E_; ++i) { ex[i] = expf(logits[i] - mx); se += ex[i]; }
    const float inv = 1.0f / se;
    for (int i = 0; i < E_; ++i) probs_out[b * E_ + i] = ex[i] * inv;
    chosen_out_f[b] = (float)arg;
    chosen_ws[b] = arg;
  }
}

// ---------------- batched GEMM, multi-block-per-CU implicit-overlap regime ----------------
// Regime change vs R3 (which was barrier-lockstep 8-wave, 2 waves/SIMD, measured per-phase
// = LDS + MFMA + sync fully SERIALIZED): small per-wave tiles (64x64, acc=64 VGPR) capped at
// 128 VGPR so 2-3 independent blocks co-reside per CU (4 waves/SIMD for gemm1, 3 for gemm2).
// Desynced blocks fill each other's pipe bubbles (m97/m114 measured regime, 874-912 TF).
// BK=32, 4-slot XOR swizzle: slot p of row r (row = 32 bf16 = 4x16B) holds logical k-chunk
// p^(r&3); staging src-k is lane-pure; fragment reads hit all 32 banks evenly (verified
// conflict-free in earlier session). Triple-buffered LDS, ONE counted vmcnt(NCALL) +
// ONE barrier per K-tile: stage(t+2) issued at tile t, vmcnt guarantees t+1 landed with
// t+2's calls still in flight (~2 tiles of latency cover; never drains mid-loop).
// lgkmcnt: compiler-managed fine-grained waits (ds_reads feed MFMAs by data dependence).
template <int K, int N, int BM, int BN, int WM, int WN, int THREADS, int MINW,
          bool RELU, bool BOUNCE, typename OutT>
__global__ __launch_bounds__(THREADS, MINW)
void gemm_mb_kernel(const __bf16* __restrict__ Aall, const __bf16* __restrict__ BTall,
                    const float* __restrict__ biasAll, OutT* __restrict__ Call,
                    const int* __restrict__ chosen) {
  static_assert(BM == WM * 64 && BN == WN * 64, "per-wave 64x64");
  static_assert(THREADS == WM * WN * 64, "one wave per 64x64 subtile");
  constexpr int NT = K / 32;                      // K-tiles
  constexpr int NTN = N / BN;
  constexpr int TILES = (512 / BM) * NTN;
  constexpr int CALLA = (BM * 64) / (THREADS * 16);   // global_load_lds calls for A-tile
  constexpr int CALLB = (BN * 64) / (THREADS * 16);
  constexpr int NCALL = CALLA + CALLB;
  constexpr int CPX = (B_ * TILES) / 8;

  __shared__ __bf16 As[3][BM * 32];
  __shared__ __bf16 Bs[3][BN * 32];
  __shared__ int zmap[B_];

  const int tid = threadIdx.x;

  // XCD-chunked bijective swizzle + expert-sorted utterance order (L2 weight locality)
  const int Lw = (blockIdx.x & 7) * CPX + (blockIdx.x >> 3);
  const int zi = Lw / TILES, tile = Lw % TILES;
  if (tid < B_) {
    const int key = chosen[tid] * B_ + tid;
    int r = 0;
    for (int b2 = 0; b2 < B_; ++b2) r += (chosen[b2] * B_ + b2) < key;
    zmap[r] = tid;
  }
  __syncthreads();
  const int b = zmap[zi];
  const int e = chosen[b];

  const __bf16* A  = Aall  + (size_t)b * 512 * K;
  const __bf16* BT = BTall + (size_t)e * N * K;
  const float* bias = biasAll + (size_t)e * N;
  OutT* C = Call + (size_t)b * 512 * N;
  const int m0 = (tile / NTN) * BM;
  const int n0 = (tile % NTN) * BN;

  const int lane = tid & 63;
  const int w    = tid >> 6;
  const int wm = w / WN, wn = w % WN;
  const int l16  = lane & 15;
  const int quad = lane >> 4;
  // staging: thread covers row (lane>>2) of its 16-row group, phys slot lane&3;
  // source k-chunk = phys ^ (row&3)  (lane-pure)
  const int qsrc = ((lane & 3) ^ ((lane >> 2) & 3)) * 8;
  // reads: phys slot = quad ^ (row&3); row&3 == l16&3 for all fragment rows
  const int slot8 = (quad ^ (l16 & 3)) * 8;
  const int aoff = (wm * 64 + l16) * 32 + slot8;    // elem offset within an A buffer
  const int boff = (wn * 64 + l16) * 32 + slot8;

  auto stage = [&](int buf, int t) {
#pragma unroll
    for (int c = 0; c < CALLA; ++c)
      __builtin_amdgcn_global_load_lds(
          AS1C(A + (size_t)(m0 + c * (THREADS / 4) + w * 16 + (lane >> 2)) * K + t * 32 + qsrc),
          AS3(&As[buf][c * THREADS * 8 + w * 512]), 16, 0, 0);
#pragma unroll
    for (int c = 0; c < CALLB; ++c)
      __builtin_amdgcn_global_load_lds(
          AS1C(BT + (size_t)(n0 + c * (THREADS / 4) + w * 16 + (lane >> 2)) * K + t * 32 + qsrc),
          AS3(&Bs[buf][c * THREADS * 8 + w * 512]), 16, 0, 0);
  };

  f32x4 acc[4][4] = {};

  // prologue: stage tiles 0,1; counted wait -> tile0 landed, tile1 in flight
  stage(0, 0); stage(1, 1);
  asm volatile("s_waitcnt vmcnt(%0)" :: "n"(NCALL) : "memory");
  __builtin_amdgcn_s_barrier();

  int cur = 0;
  for (int t = 0; t < NT; ++t) {
    const int nx = (cur >= 1) ? cur - 1 : cur + 2;          // (t+2)%3
    if (t + 2 < NT) stage(nx, t + 2);
    bf16x8 af[4];
#pragma unroll
    for (int i = 0; i < 4; ++i)
      af[i] = *reinterpret_cast<const bf16x8*>(&As[cur][aoff + i * 512]);
#pragma unroll
    for (int j = 0; j < 4; ++j) {
      const bf16x8 bj = *reinterpret_cast<const bf16x8*>(&Bs[cur][boff + j * 512]);
#pragma unroll
      for (int i = 0; i < 4; ++i)
        acc[i][j] = __builtin_amdgcn_mfma_f32_16x16x32_bf16(af[i], bj, acc[i][j], 0, 0, 0);
    }
    if (t + 2 < NT)      asm volatile("s_waitcnt vmcnt(%0)" :: "n"(NCALL) : "memory");
    else if (t + 1 < NT) asm volatile("s_waitcnt vmcnt(0)" ::: "memory");
    if (t + 1 < NT) __builtin_amdgcn_s_barrier();
    cur = (cur + 1 == 3) ? 0 : cur + 1;
  }

  float bv[4];
#pragma unroll
  for (int j = 0; j < 4; ++j) bv[j] = bias[n0 + wn * 64 + j * 16 + l16];

  if (BOUNCE) {
    // bf16 out: per-wave private 8KB LDS bounce (XOR row-swizzle), then coalesced bf16x8
    // stores (full sectors; direct 2B stores measured 4.2x write-amp in R1).
    __builtin_amdgcn_s_barrier();    // all waves done reading K-loop LDS
    __bf16* wl = (w < 2 * WM * WN - 2) ? (&As[0][0] + w * 4096)
                                       : (&Bs[0][0] + (w - (2 * WM * WN - 2)) * 4096);
#pragma unroll
    for (int i = 0; i < 4; ++i)
#pragma unroll
      for (int r = 0; r < 4; ++r) {
        const int L = i * 16 + quad * 4 + r;
        const int key = (L & 7) << 3;
#pragma unroll
        for (int j = 0; j < 4; ++j) {
          float v = acc[i][j][r] + bv[j];
          if (RELU) v = fmaxf(v, 0.f);
          wl[L * 64 + ((j * 16 + l16) ^ key)] = (__bf16)v;
        }
      }
#pragma unroll
    for (int it = 0; it < 8; ++it) {
      const int L = it * 8 + (lane >> 3);
      const int p = lane & 7;
      bf16x8 vrow = *reinterpret_cast<const bf16x8*>(&wl[L * 64 + p * 8]);
      const int lc = (p ^ (L & 7)) * 8;
      const int gm = m0 + wm * 64 + L;
      const int gn = n0 + wn * 64 + lc;
      *reinterpret_cast<bf16x8*>(&((__bf16*)C)[(size_t)gm * N + gn]) = vrow;
    }
  } else {
    // f32 out: direct stores, 16 lanes x 4B = 64B sectors (no write amp)
#pragma unroll
    for (int i = 0; i < 4; ++i) {
      const int gm = m0 + wm * 64 + i * 16 + quad * 4;
#pragma unroll
      for (int r = 0; r < 4; ++r) {
        OutT* Crow = C + (size_t)(gm + r) * N;
#pragma unroll
        for (int j = 0; j < 4; ++j) {
          float v = acc[i][j][r] + bv[j];
          if (RELU) v = fmaxf(v, 0.f);
          Crow[n0 + wn * 64 + j * 16 + l16] = (OutT)v;
        }
      }
    }
  }
}

extern "C" void kernel_launch(void* const* d_in, const int* in_sizes, int n_in,
                              void* d_out, int out_size, void* d_ws, size_t ws_size,
                              hipStream_t stream) {
  const float* x  = (const float*)d_in[0];
  const float* Wp = (const float*)d_in[1];
  const float* bp = (const float*)d_in[2];
  const float* W1 = (const float*)d_in[3];
  const float* b1 = (const float*)d_in[4];
  const float* W2 = (const float*)d_in[5];
  const float* b2 = (const float*)d_in[6];
  float* out = (float*)d_out;

  char* ws = (char*)d_ws;
  int*    chosen = (int*)ws;
  __bf16* xbf  = (__bf16*)(ws + 256);                          // 16 MB
  __bf16* w1t  = (__bf16*)(ws + 256 + (size_t)16777216);       // 16 MB  [E,H,D]
  __bf16* w2t  = (__bf16*)(ws + 256 + (size_t)2 * 16777216);   // 16 MB  [E,D,H]
  __bf16* hbuf = (__bf16*)(ws + 256 + (size_t)3 * 16777216);   // 64 MB  [B,T,H]

  float* final_out  = out;                                // [B,T,D]
  float* probs_out  = out + (size_t)B_ * T_ * D_;         // [B,E]
  float* chosen_out = probs_out + B_ * E_;                // [B,1] as float
  float* partial = out;  // [B][P_][D] = 2 MB, consumed by router2 before gemm2 overwrites

  prep_kernel<<<dim3(B_ * S_ + 16 * 256), 256, 0, stream>>>(x, xbf, partial, W1, W2, w1t, w2t);
  router2_kernel<<<B_, 512, 0, stream>>>(partial, Wp, bp, probs_out, chosen_out, chosen);

  // h = relu(x @ W1[e] + b1[e]) : M=512,K=512,N=2048. 256x128 tile, 8 waves of 64x64,
  // 72KB LDS x 2 blocks/CU = 4 waves/SIMD (VGPR capped 128). 1024 blocks.
  gemm_mb_kernel<512, 2048, 256, 128, 4, 2, 512, 4, true, true, __bf16>
      <<<dim3(1024), 512, 0, stream>>>(xbf, w1t, b1, hbuf, chosen);
  // out = h @ W2[e] + b2[e] : M=512,K=2048,N=512. 128x128 tile, 4 waves of 64x64,
  // 48KB LDS x 3 blocks/CU = 3 waves/SIMD. 512 blocks.
  gemm_mb_kernel<2048, 512, 128, 128, 2, 2, 256, 3, false, false, float>
      <<<dim3(512), 256, 0, stream>>>(hbuf, w2t, b2, final_out, chosen);
}

// Round 5
// 236.166 us; speedup vs baseline: 1.0842x; 1.0222x over previous
//
#include <hip/hip_runtime.h>
#include <cstdint>

#define AS1C(p) ((const __attribute__((address_space(1))) void*)(p))
#define AS3(p)  ((__attribute__((address_space(3))) void*)(p))

typedef __bf16 bf16x8 __attribute__((ext_vector_type(8)));
typedef __bf16 bf16x4 __attribute__((ext_vector_type(4)));
typedef float  f32x4  __attribute__((ext_vector_type(4)));

constexpr int B_ = 32, T_ = 512, D_ = 512, E_ = 8, H_ = 2048;
constexpr int S_ = 16;   // pool blocks per utterance
constexpr int P_ = 32;   // partial slots per utterance (2 per pool block)

// ---------------- fused prep: x->bf16 + partial mean-pool, and W1/W2 transpose+cvt ----------------
__global__ __launch_bounds__(256)
void prep_kernel(const float* __restrict__ x, __bf16* __restrict__ xbf,
                 float* __restrict__ partial /*[B][P_][D]*/,
                 const float* __restrict__ W1, const float* __restrict__ W2,
                 __bf16* __restrict__ w1t, __bf16* __restrict__ w2t) {
  __shared__ float t[64][65];
  const int blk = blockIdx.x;
  const int tid = threadIdx.x;
  if (blk < B_ * S_) {
    const int b = blk >> 4, s = blk & 15;
    const int c = (tid & 127) * 4;
    const int half = tid >> 7;
    const size_t base = (size_t)b * T_ * D_ + (size_t)(s * 32) * D_;
    const float* xb = x + base;
    __bf16* ob = xbf + base;
    f32x4 acc = {0.f, 0.f, 0.f, 0.f};
#pragma unroll
    for (int i = 0; i < 16; ++i) {
      const int tr = half + 2 * i;
      f32x4 v = *reinterpret_cast<const f32x4*>(&xb[(size_t)tr * D_ + c]);
      acc += v;
      bf16x4 h; h[0] = (__bf16)v[0]; h[1] = (__bf16)v[1]; h[2] = (__bf16)v[2]; h[3] = (__bf16)v[3];
      *reinterpret_cast<bf16x4*>(&ob[(size_t)tr * D_ + c]) = h;
    }
    float* p = partial + ((size_t)b * P_ + (s * 2 + half)) * D_ + c;
    *reinterpret_cast<f32x4*>(p) = acc;
  } else {
    const int idx = blk - B_ * S_;
    const int z = idx >> 8;
    const int tt = idx & 255;
    const float* src; __bf16* dst; int R, C;
    if (z < E_) { src = W1 + (size_t)z * D_ * H_; dst = w1t + (size_t)z * D_ * H_; R = D_; C = H_; }
    else        { src = W2 + (size_t)(z - E_) * H_ * D_; dst = w2t + (size_t)(z - E_) * H_ * D_; R = H_; C = D_; }
    const int nTc = C >> 6;
    const int c0 = (tt % nTc) * 64;
    const int r0 = (tt / nTc) * 64;
    const int lx = tid & 15, ly = tid >> 4;
#pragma unroll
    for (int i = 0; i < 4; ++i) {
      const int r = ly + i * 16;
      float4 v = *reinterpret_cast<const float4*>(&src[(size_t)(r0 + r) * C + c0 + lx * 4]);
      t[r][lx * 4 + 0] = v.x; t[r][lx * 4 + 1] = v.y;
      t[r][lx * 4 + 2] = v.z; t[r][lx * 4 + 3] = v.w;
    }
    __syncthreads();
#pragma unroll
    for (int h = 0; h < 2; ++h) {
      const int chunk = tid + h * 256;
      const int cc = chunk >> 3;
      const int rr = (chunk & 7) * 8;
      bf16x8 o;
#pragma unroll
      for (int j = 0; j < 8; ++j) o[j] = (__bf16)t[rr + j][cc];
      *reinterpret_cast<bf16x8*>(&dst[(size_t)(c0 + cc) * R + r0 + rr]) = o;
    }
  }
}

// ---------------- router finisher ----------------
__global__ void router2_kernel(const float* __restrict__ partial, const float* __restrict__ Wp,
                               const float* __restrict__ bp, float* __restrict__ probs_out,
                               float* __restrict__ chosen_out_f, int* __restrict__ chosen_ws) {
  const int b = blockIdx.x;
  const int tid = threadIdx.x;  // 512 threads, one per d
  __shared__ float pooled[D_];
  __shared__ float part[E_][64];
  __shared__ float logits[E_];
  const float* p = partial + (size_t)b * P_ * D_;
  float s = 0.f;
#pragma unroll
  for (int i = 0; i < P_; ++i) s += p[i * D_ + tid];
  pooled[tid] = s * (1.0f / (float)T_);
  __syncthreads();
  const int e = tid >> 6, dl = tid & 63;
  float acc = 0.f;
  for (int d = dl; d < D_; d += 64) acc += pooled[d] * Wp[d * E_ + e];
  part[e][dl] = acc;
  __syncthreads();
  if (tid < E_) {
    float sum = bp[tid];
#pragma unroll
    for (int i = 0; i < 64; ++i) sum += part[tid][i];
    logits[tid] = sum;
  }
  __syncthreads();
  if (tid == 0) {
    float mx = logits[0]; int arg = 0;
    for (int i = 1; i < E_; ++i) if (logits[i] > mx) { mx = logits[i]; arg = i; }
    float ex[E_], se = 0.f;
    for (int i = 0; i < E_; ++i) { ex[i] = expf(logits[i] - mx); se += ex[i]; }
    const float inv = 1.0f / se;
    for (int i = 0; i < E_; ++i) probs_out[b * E_ + i] = ex[i] * inv;
    chosen_out_f[b] = (float)arg;
    chosen_ws[b] = arg;
  }
}

// ---------------- unified batched GEMM: mb-regime + BK=64 zero-conflict layout ----------------
// C[b] = epilogue(A[b] @ BT[e]^T + bias[e]); A:[512,K] k-contig, BT:[N,K] k-contig.
// Synthesis of R4's winner (gemm1-mb ~41us inferred) with the conflict fix:
//  - 128x128 tile, 4 waves of 64x64, 256 thr; 64KB LDS -> 2 blocks/CU co-resident.
//    Desynced blocks fill each other's pipe bubbles (m97/m114 regime; the only structure
//    that moved gemm1: 53 -> ~41us).
//  - BK=64, 128B LDS rows, 8-slot XOR swizzle (slot p of row r = kchunk p^(r&7)): measured
//    ZERO bank conflicts in R0-R3. The R4 BK=32/64B-row layout measured exactly 4.0
//    conflicts per ds_read_b128 (4.2M total) - reverted.
//  - Per K-tile: stage(t+1) into s^1 FIRST, then 16 ds_read_b128 + 32 MFMA on s (compiler
//    inserts fine-grained lgkmcnt), then ONE vmcnt(0)+s_barrier. Cover for the staged loads
//    = the whole tile's compute (~700-1200cy >= L2/L3 latency) + cross-block overlap.
//    Half the barriers of R4 (1 per 64-K vs 1 per 32-K), 2x MFMA per barrier-pair.
// Grids: gemm1 2048 blocks (8/CU stream), gemm2 512 (2/CU).
template <int K, int N, bool RELU, bool BOUNCE, typename OutT>
__global__ __launch_bounds__(256, 2)
void gemm_u_kernel(const __bf16* __restrict__ Aall, const __bf16* __restrict__ BTall,
                   const float* __restrict__ biasAll, OutT* __restrict__ Call,
                   const int* __restrict__ chosen) {
  constexpr int BM = 128, BN = 128;
  constexpr int NT = K / 64;                  // K-tiles
  constexpr int NTN = N / BN;                 // n-tiles per utterance
  constexpr int TILES = (512 / BM) * NTN;     // tiles per utterance
  constexpr int CPX = (B_ * TILES) / 8;       // blocks per XCD chunk

  __shared__ __bf16 As[2][BM * 64];  // 32 KB
  __shared__ __bf16 Bs[2][BN * 64];  // 32 KB
  __shared__ int zmap[B_];

  const int tid = threadIdx.x;

  // XCD-chunked bijective swizzle + expert-sorted utterance order (L2 weight locality;
  // FETCH_SIZE 87MB -> 27MB measured when introduced in R1)
  const int Lw = (blockIdx.x & 7) * CPX + (blockIdx.x >> 3);
  const int zi = Lw / TILES, tile = Lw % TILES;
  if (tid < B_) {
    const int key = chosen[tid] * B_ + tid;
    int r = 0;
    for (int b2 = 0; b2 < B_; ++b2) r += (chosen[b2] * B_ + b2) < key;
    zmap[r] = tid;
  }
  __syncthreads();
  const int b = zmap[zi];
  const int e = chosen[b];

  const __bf16* A  = Aall  + (size_t)b * 512 * K;
  const __bf16* BT = BTall + (size_t)e * N * K;
  const float* bias = biasAll + (size_t)e * N;
  OutT* C = Call + (size_t)b * 512 * N;
  const int m0 = (tile / NTN) * BM;
  const int n0 = (tile % NTN) * BN;

  const int lane = tid & 63;
  const int w    = tid >> 6;
  const int wm = w >> 1, wn = w & 1;          // 2x2 wave grid, per-wave 64x64
  const int l16  = lane & 15;
  const int quad = lane >> 4;
  const int lr8  = lane >> 3;                 // staging row-within-8
  const int qsrc = ((lane & 7) ^ lr8) * 8;    // swizzled source k-offset (lane-pure)
  const int swl  = l16 & 7;                   // read-side row swizzle key

  // staging: 8 global_load_lds per tile (4 A + 4 B), each covers 32 rows of 128B
  auto stage = [&](int s, int t) {
#pragma unroll
    for (int j = 0; j < 4; ++j) {
      const int r = (w * 4 + j) * 8 + lr8;
      __builtin_amdgcn_global_load_lds(AS1C(A + (size_t)(m0 + r) * K + t * 64 + qsrc),
                                       AS3(&As[s][(w * 4 + j) * 512]), 16, 0, 0);
      __builtin_amdgcn_global_load_lds(AS1C(BT + (size_t)(n0 + r) * K + t * 64 + qsrc),
                                       AS3(&Bs[s][(w * 4 + j) * 512]), 16, 0, 0);
    }
  };

  f32x4 acc[4][4] = {};

  auto compute = [&](int s) {
    __builtin_amdgcn_s_setprio(1);
#pragma unroll
    for (int h = 0; h < 2; ++h) {                   // two k-halves of 32
      const int ls = ((h * 4 + quad) ^ swl) * 8;    // physical slot offset (bf16 elems)
      bf16x8 af[4], bfr[4];
#pragma unroll
      for (int i = 0; i < 4; ++i) {
        af[i]  = *reinterpret_cast<const bf16x8*>(&As[s][(wm * 64 + i * 16 + l16) * 64 + ls]);
        bfr[i] = *reinterpret_cast<const bf16x8*>(&Bs[s][(wn * 64 + i * 16 + l16) * 64 + ls]);
      }
#pragma unroll
      for (int i = 0; i < 4; ++i)
#pragma unroll
        for (int j = 0; j < 4; ++j)
          acc[i][j] = __builtin_amdgcn_mfma_f32_16x16x32_bf16(af[i], bfr[j], acc[i][j], 0, 0, 0);
    }
    __builtin_amdgcn_s_setprio(0);
  };

  // prologue: tile 0 must land before first reads (block-stagger hides this latency)
  stage(0, 0);
  asm volatile("s_waitcnt vmcnt(0)" ::: "memory");
  __builtin_amdgcn_s_barrier();

  int s = 0;
  for (int t = 0; t < NT; ++t) {
    if (t + 1 < NT) stage(s ^ 1, t + 1);  // issue next-tile loads BEFORE compute
    compute(s);
    if (t + 1 < NT) {
      asm volatile("s_waitcnt vmcnt(0)" ::: "memory");  // t+1 landed (issued ~1 tile ago)
      __builtin_amdgcn_s_barrier();
    }
    s ^= 1;
  }

  float bv[4];
#pragma unroll
  for (int j = 0; j < 4; ++j) bv[j] = bias[n0 + wn * 64 + j * 16 + l16];

  if (BOUNCE) {
    // bf16 out: per-wave private 8KB LDS bounce (XOR row-swizzle), coalesced bf16x8 stores
    // (direct 2B scatter stores measured 4.2x HBM write-amp in R1: 140MB for 33.5MB logical)
    __builtin_amdgcn_s_barrier();    // all waves done reading K-loop LDS
    __bf16* wl = &As[0][0] + w * 4096;
#pragma unroll
    for (int i = 0; i < 4; ++i)
#pragma unroll
      for (int r = 0; r < 4; ++r) {
        const int L = i * 16 + quad * 4 + r;
        const int key = (L & 7) << 3;
#pragma unroll
        for (int j = 0; j < 4; ++j) {
          float v = acc[i][j][r] + bv[j];
          if (RELU) v = fmaxf(v, 0.f);
          wl[L * 64 + ((j * 16 + l16) ^ key)] = (__bf16)v;
        }
      }
#pragma unroll
    for (int it = 0; it < 8; ++it) {
      const int L = it * 8 + (lane >> 3);
      const int p = lane & 7;
      bf16x8 vrow = *reinterpret_cast<const bf16x8*>(&wl[L * 64 + p * 8]);
      const int lc = (p ^ (L & 7)) * 8;
      const int gm = m0 + wm * 64 + L;
      const int gn = n0 + wn * 64 + lc;
      *reinterpret_cast<bf16x8*>(&((__bf16*)C)[(size_t)gm * N + gn]) = vrow;
    }
  } else {
    // f32 out: direct stores, 16 lanes x 4B = 64B sectors (no write amp; R4 measured 33MB)
#pragma unroll
    for (int i = 0; i < 4; ++i) {
      const int gm = m0 + wm * 64 + i * 16 + quad * 4;
#pragma unroll
      for (int r = 0; r < 4; ++r) {
        OutT* Crow = C + (size_t)(gm + r) * N;
#pragma unroll
        for (int j = 0; j < 4; ++j) {
          float v = acc[i][j][r] + bv[j];
          if (RELU) v = fmaxf(v, 0.f);
          Crow[n0 + wn * 64 + j * 16 + l16] = (OutT)v;
        }
      }
    }
  }
}

extern "C" void kernel_launch(void* const* d_in, const int* in_sizes, int n_in,
                              void* d_out, int out_size, void* d_ws, size_t ws_size,
                              hipStream_t stream) {
  const float* x  = (const float*)d_in[0];
  const float* Wp = (const float*)d_in[1];
  const float* bp = (const float*)d_in[2];
  const float* W1 = (const float*)d_in[3];
  const float* b1 = (const float*)d_in[4];
  const float* W2 = (const float*)d_in[5];
  const float* b2 = (const float*)d_in[6];
  float* out = (float*)d_out;

  char* ws = (char*)d_ws;
  int*    chosen = (int*)ws;
  __bf16* xbf  = (__bf16*)(ws + 256);                          // 16 MB
  __bf16* w1t  = (__bf16*)(ws + 256 + (size_t)16777216);       // 16 MB  [E,H,D]
  __bf16* w2t  = (__bf16*)(ws + 256 + (size_t)2 * 16777216);   // 16 MB  [E,D,H]
  __bf16* hbuf = (__bf16*)(ws + 256 + (size_t)3 * 16777216);   // 64 MB  [B,T,H]

  float* final_out  = out;                                // [B,T,D]
  float* probs_out  = out + (size_t)B_ * T_ * D_;         // [B,E]
  float* chosen_out = probs_out + B_ * E_;                // [B,1] as float
  float* partial = out;  // [B][P_][D] = 2 MB, consumed by router2 before gemm2 overwrites

  prep_kernel<<<dim3(B_ * S_ + 16 * 256), 256, 0, stream>>>(x, xbf, partial, W1, W2, w1t, w2t);
  router2_kernel<<<B_, 512, 0, stream>>>(partial, Wp, bp, probs_out, chosen_out, chosen);

  // h = relu(x @ W1[e] + b1[e]) : M=512,K=512,N=2048. 64 tiles/utt -> 2048 blocks (8/CU stream).
  gemm_u_kernel<512, 2048, true, true, __bf16>
      <<<dim3(2048), 256, 0, stream>>>(xbf, w1t, b1, hbuf, chosen);
  // out = h @ W2[e] + b2[e] : M=512,K=2048,N=512. 16 tiles/utt -> 512 blocks (2/CU).
  gemm_u_kernel<2048, 512, false, false, float>
      <<<dim3(512), 256, 0, stream>>>(hbuf, w2t, b2, final_out, chosen);
}